// Round 3
// baseline (403.610 us; speedup 1.0000x reference)
//
#include <hip/hip_runtime.h>
#include <float.h>

#define NSEG 4096
#define CAP 2048   // max edges/segment held in LDS (binomial(1M,1/4096) max ~330)

// ---- segment boundaries: segs[b] = first edge index with batch >= b ----
__global__ void seg_bounds(const int* __restrict__ batch, int* __restrict__ segs, int E) {
  int b = blockIdx.x * blockDim.x + threadIdx.x;
  if (b > NSEG) return;
  int lo = 0, hi = E;
  while (lo < hi) { int mid = (lo + hi) >> 1; if (batch[mid] < b) lo = mid + 1; else hi = mid; }
  segs[b] = lo;
}

// Y = X @ W (+bias for blockIdx.y==1); X: nrows x 128, W: 128 x 128 row-major.
// 128 threads/block, 64 rows/block, 8x8 micro-tile per thread (64 FMA/k-step).
// X tile in LDS row-major pitch 130: x-reads are 16-lane broadcasts with only a
// free 2-way tr-alias; W streamed from global (64KB, L1/L2-hot) with 1-iter
// manual prefetch so vmcnt waits hide behind 64 FMAs.
#define XP 130
__global__ __launch_bounds__(128, 2) void proj_gemm(
    const float* __restrict__ Xj, const float* __restrict__ Wj,
    const float* __restrict__ Xi, const float* __restrict__ Wi,
    const float* __restrict__ bias,
    float* __restrict__ Yj, float* __restrict__ Yi, int nrows) {
  const int which = blockIdx.y;
  const float* X = which ? Xi : Xj;
  const float* W = which ? Wi : Wj;
  float* Y = which ? Yi : Yj;

  __shared__ float xs[64 * XP];
  const int tid = threadIdx.x;
  const long base = (long)blockIdx.x * (64 * 128);
  const long total = (long)nrows * 128;
  // stage 64x128 X tile (2048 float4, 16 per thread)
  #pragma unroll
  for (int i = 0; i < 16; ++i) {
    int idx = tid + i * 128;
    int row = idx >> 5;          // 32 float4 per row
    int col4 = idx & 31;
    long ge = base + (long)idx * 4;
    float4 v = make_float4(0.f, 0.f, 0.f, 0.f);
    if (ge + 3 < total) v = *(const float4*)(X + ge);
    float* dst = xs + row * XP + col4 * 4;
    // two b64 writes (8B-aligned: 130*row + 4*col4 is even)
    *(float2*)(dst) = make_float2(v.x, v.y);
    *(float2*)(dst + 2) = make_float2(v.z, v.w);
  }
  __syncthreads();

  const int tr = tid >> 4;     // 0..7 -> rows tr*8..+7
  const int tc = tid & 15;     // 0..15 -> cols tc*8..+7
  const int r0 = tr * 8;
  const int c0 = tc * 8;

  float acc[8][8] = {};
  const float* Wp = W + c0;
  float4 w0 = *(const float4*)(Wp);
  float4 w1 = *(const float4*)(Wp + 4);
  #pragma unroll 4
  for (int k = 0; k < 127; ++k) {
    float4 nw0 = *(const float4*)(Wp + (k + 1) * 128);
    float4 nw1 = *(const float4*)(Wp + (k + 1) * 128 + 4);
    float xv[8];
    #pragma unroll
    for (int j = 0; j < 8; ++j) xv[j] = xs[(r0 + j) * XP + k];
    #pragma unroll
    for (int r = 0; r < 8; ++r) {
      acc[r][0] += xv[r] * w0.x; acc[r][1] += xv[r] * w0.y;
      acc[r][2] += xv[r] * w0.z; acc[r][3] += xv[r] * w0.w;
      acc[r][4] += xv[r] * w1.x; acc[r][5] += xv[r] * w1.y;
      acc[r][6] += xv[r] * w1.z; acc[r][7] += xv[r] * w1.w;
    }
    w0 = nw0; w1 = nw1;
  }
  {
    float xv[8];
    #pragma unroll
    for (int j = 0; j < 8; ++j) xv[j] = xs[(r0 + j) * XP + 127];
    #pragma unroll
    for (int r = 0; r < 8; ++r) {
      acc[r][0] += xv[r] * w0.x; acc[r][1] += xv[r] * w0.y;
      acc[r][2] += xv[r] * w0.z; acc[r][3] += xv[r] * w0.w;
      acc[r][4] += xv[r] * w1.x; acc[r][5] += xv[r] * w1.y;
      acc[r][6] += xv[r] * w1.z; acc[r][7] += xv[r] * w1.w;
    }
  }

  float4 b0 = make_float4(0.f, 0.f, 0.f, 0.f), b1 = b0;
  if (which) { b0 = *(const float4*)(bias + c0); b1 = *(const float4*)(bias + c0 + 4); }
  const long rowBase = (long)blockIdx.x * 64 + r0;
  #pragma unroll
  for (int r = 0; r < 8; ++r) {
    long row = rowBase + r;
    if (row < nrows) {
      *(float4*)(Y + row * 128 + c0) =
          make_float4(acc[r][0] + b0.x, acc[r][1] + b0.y, acc[r][2] + b0.z, acc[r][3] + b0.w);
      *(float4*)(Y + row * 128 + c0 + 4) =
          make_float4(acc[r][4] + b1.x, acc[r][5] + b1.y, acc[r][6] + b1.z, acc[r][7] + b1.w);
    }
  }
}

// One block per segment. Phase 1: alpha per edge (half-wave/edge, dual-edge
// unrolled -> 4 gathers in flight per wave). Phase 2-4: block softmax. No atomics.
__global__ __launch_bounds__(256) void seg_softmax(
    const float* __restrict__ xjp, const float* __restrict__ xip,
    const int* __restrict__ ei, const int* __restrict__ segs,
    const float* __restrict__ mlpW, const float* __restrict__ prelu_w,
    const float* __restrict__ mlp_b, float* __restrict__ out, int E) {
  const int start = segs[blockIdx.x];
  const int end = segs[blockIdx.x + 1];
  const int cnt = end - start;
  if (cnt <= 0) return;

  __shared__ float aS[CAP];
  __shared__ float red[8];

  const int tid = threadIdx.x;
  const int lane = tid & 63;
  const int sl = lane & 31;          // lane within half-wave
  const int slot = tid >> 5;         // 8 half-wave edge slots per block
  const int wid = tid >> 6;

  const float4 w = *(const float4*)(mlpW + sl * 4);
  const float pw = prelu_w[0];
  const float mb = mlp_b[0];
  const bool useLds = (cnt <= CAP);

  // ---- phase 1: alpha ----
  for (int e = start + slot; e < end; e += 16) {
    int e2 = e + 8;
    bool v2 = (e2 < end);
    int s1 = ei[e], d1 = ei[E + e];
    int s2 = v2 ? ei[e2] : s1;
    int d2 = v2 ? ei[E + e2] : d1;
    float4 a1 = *(const float4*)(xjp + (long)s1 * 128 + sl * 4);
    float4 b1 = *(const float4*)(xip + (long)d1 * 128 + sl * 4);
    float4 a2 = *(const float4*)(xjp + (long)s2 * 128 + sl * 4);
    float4 b2 = *(const float4*)(xip + (long)d2 * 128 + sl * 4);

    float h0 = a1.x + b1.x, h1 = a1.y + b1.y, h2 = a1.z + b1.z, h3 = a1.w + b1.w;
    h0 = h0 >= 0.f ? h0 : pw * h0; h1 = h1 >= 0.f ? h1 : pw * h1;
    h2 = h2 >= 0.f ? h2 : pw * h2; h3 = h3 >= 0.f ? h3 : pw * h3;
    float p1 = h0 * w.x + h1 * w.y + h2 * w.z + h3 * w.w;

    float g0 = a2.x + b2.x, g1 = a2.y + b2.y, g2 = a2.z + b2.z, g3 = a2.w + b2.w;
    g0 = g0 >= 0.f ? g0 : pw * g0; g1 = g1 >= 0.f ? g1 : pw * g1;
    g2 = g2 >= 0.f ? g2 : pw * g2; g3 = g3 >= 0.f ? g3 : pw * g3;
    float p2 = g0 * w.x + g1 * w.y + g2 * w.z + g3 * w.w;

    #pragma unroll
    for (int off = 1; off < 32; off <<= 1) {
      p1 += __shfl_xor(p1, off, 64);
      p2 += __shfl_xor(p2, off, 64);
    }
    if (sl == 0) {
      float av1 = p1 + mb;
      if (useLds) aS[e - start] = av1; else out[e] = av1;
      if (v2) {
        float av2 = p2 + mb;
        if (useLds) aS[e2 - start] = av2; else out[e2] = av2;
      }
    }
  }
  __syncthreads();

  // ---- phase 2: block max ----
  float m = -FLT_MAX;
  if (useLds) { for (int i = tid; i < cnt; i += 256) m = fmaxf(m, aS[i]); }
  else        { for (int i = tid; i < cnt; i += 256) m = fmaxf(m, out[start + i]); }
  #pragma unroll
  for (int off = 1; off < 64; off <<= 1) m = fmaxf(m, __shfl_xor(m, off, 64));
  if (lane == 0) red[wid] = m;
  __syncthreads();
  m = fmaxf(fmaxf(red[0], red[1]), fmaxf(red[2], red[3]));

  // ---- phase 3: exp + block sum ----
  float s = 0.f;
  if (useLds) {
    for (int i = tid; i < cnt; i += 256) { float x = expf(aS[i] - m); aS[i] = x; s += x; }
  } else {
    for (int i = tid; i < cnt; i += 256) { float x = expf(out[start + i] - m); out[start + i] = x; s += x; }
  }
  #pragma unroll
  for (int off = 1; off < 64; off <<= 1) s += __shfl_xor(s, off, 64);
  if (lane == 0) red[4 + wid] = s;
  __syncthreads();
  s = (red[4] + red[5]) + (red[6] + red[7]);

  // ---- phase 4: normalize + write ----
  const float inv = 1.0f / (s + 1e-16f);
  if (useLds) { for (int i = tid; i < cnt; i += 256) out[start + i] = aS[i] * inv; }
  else        { for (int i = tid; i < cnt; i += 256) out[start + i] *= inv; }
}

extern "C" void kernel_launch(void* const* d_in, const int* in_sizes, int n_in,
                              void* d_out, int out_size, void* d_ws, size_t ws_size,
                              hipStream_t stream) {
  const float* x_j      = (const float*)d_in[0];
  const float* x_i      = (const float*)d_in[1];
  const int*   edge_idx = (const int*)d_in[2];
  const int*   batch    = (const int*)d_in[3];
  const float* w_j      = (const float*)d_in[4];
  const float* w_i      = (const float*)d_in[5];
  const float* bias     = (const float*)d_in[6];
  const float* prelu_w  = (const float*)d_in[7];
  const float* mlp_W    = (const float*)d_in[8];
  const float* mlp_b    = (const float*)d_in[9];
  const int nnodes = in_sizes[0] / 128;
  const int E = in_sizes[3];

  float* xjp = (float*)d_ws;
  float* xip = xjp + (size_t)nnodes * 128;
  int* segs  = (int*)(xip + (size_t)nnodes * 128);

  hipLaunchKernelGGL(seg_bounds, dim3((NSEG + 1 + 255) / 256), dim3(256), 0, stream,
                     batch, segs, E);

  int gblocks = (nnodes + 63) / 64;
  hipLaunchKernelGGL(proj_gemm, dim3(gblocks, 2), dim3(128), 0, stream,
                     x_j, w_j, x_i, w_i, bias, xjp, xip, nnodes);

  hipLaunchKernelGGL(seg_softmax, dim3(NSEG), dim3(256), 0, stream,
                     xjp, xip, edge_idx, segs, mlp_W, prelu_w, mlp_b,
                     (float*)d_out, E);
}